// Round 1
// baseline (505.760 us; speedup 1.0000x reference)
//
#include <hip/hip_runtime.h>
#include <hip/hip_bf16.h>

typedef __bf16 bf16_t;
typedef __bf16 bf16x8 __attribute__((ext_vector_type(8)));
typedef __bf16 bf16x4 __attribute__((ext_vector_type(4)));
typedef float floatx4 __attribute__((ext_vector_type(4)));

#define MFMA_BF16(a, b, c) __builtin_amdgcn_mfma_f32_16x16x32_bf16((a), (b), (c), 0, 0, 0)

static constexpr int CB = 512;    // channels
static constexpr int NB = 4096;   // tokens (64*64)

// ---------- k0: x (b,c,n) f32 -> xT (b,n,c) bf16 ----------
__global__ __launch_bounds__(256) void k_transpose(const float* __restrict__ x,
                                                   bf16_t* __restrict__ xT) {
  __shared__ __align__(16) bf16_t T[64 * 72];
  const int t = threadIdx.x;
  const int b = blockIdx.z, c0 = blockIdx.y * 64, n0 = blockIdx.x * 64;
  {
    const int cl = t >> 4, nl = (t & 15) * 4;
#pragma unroll
    for (int p = 0; p < 4; ++p) {
      const int c = cl + p * 16;
      const float4 v = *reinterpret_cast<const float4*>(
          x + ((size_t)(b * CB + c0 + c) * NB) + n0 + nl);
      T[(nl + 0) * 72 + c] = (bf16_t)v.x;
      T[(nl + 1) * 72 + c] = (bf16_t)v.y;
      T[(nl + 2) * 72 + c] = (bf16_t)v.z;
      T[(nl + 3) * 72 + c] = (bf16_t)v.w;
    }
  }
  __syncthreads();
  {
    const int nr = t >> 2, ch = t & 3;
    bf16_t* op = xT + ((size_t)(b * NB + n0 + nr) * CB) + c0;
#pragma unroll
    for (int p = 0; p < 2; ++p) {
      bf16x8 v = *reinterpret_cast<const bf16x8*>(&T[nr * 72 + ch * 8 + p * 32]);
      *reinterpret_cast<bf16x8*>(op + ch * 8 + p * 32) = v;
    }
  }
}

// ---------- k1: QKV GEMM.  qkv[o,n] = sum_c W[o,c] x[c,n] + bias[o] ----------
// A = w_qkv (1536x512 f32, row-major), B = xT (b,n,c) bf16.
// Writes Q,K as [bh][n][64], V as [bh][64][n], all bf16.
__global__ __launch_bounds__(256) void k_qkv(const float* __restrict__ W,
                                             const float* __restrict__ bias,
                                             const bf16_t* __restrict__ xT,
                                             bf16_t* __restrict__ Qb,
                                             bf16_t* __restrict__ Kb,
                                             bf16_t* __restrict__ Vb) {
  __shared__ __align__(16) bf16_t As[128 * 40];
  __shared__ __align__(16) bf16_t Bs[128 * 40];
  const int t = threadIdx.x;
  const int lane = t & 63, wv = t >> 6;
  const int g = lane >> 4, c = lane & 15;
  const int wm = wv >> 1, wn = wv & 1;
  const int o0 = blockIdx.x * 128, n0 = blockIdx.y * 128;
  const int b = blockIdx.z;

  floatx4 acc[4][4] = {};

  const float* Ap = W + (size_t)o0 * CB;
  const bf16_t* Bp = xT + ((size_t)b * NB + n0) * CB;

  for (int kt = 0; kt < CB; kt += 32) {
    {
      const int row = t >> 3, c4 = (t & 7) * 4;
#pragma unroll
      for (int p = 0; p < 4; ++p) {
        const int r = row + p * 32;
        const float4 v = *reinterpret_cast<const float4*>(Ap + (size_t)r * CB + kt + c4);
        bf16x4 w4;
        w4[0] = (bf16_t)v.x; w4[1] = (bf16_t)v.y; w4[2] = (bf16_t)v.z; w4[3] = (bf16_t)v.w;
        *reinterpret_cast<bf16x4*>(&As[r * 40 + c4]) = w4;
      }
    }
    {
      const int row = t >> 2, ch = t & 3;
#pragma unroll
      for (int p = 0; p < 2; ++p) {
        const int r = row + p * 64;
        bf16x8 v = *reinterpret_cast<const bf16x8*>(Bp + (size_t)r * CB + kt + ch * 8);
        *reinterpret_cast<bf16x8*>(&Bs[r * 40 + ch * 8]) = v;
      }
    }
    __syncthreads();
    bf16x8 af[4], bfr[4];
#pragma unroll
    for (int i = 0; i < 4; ++i)
      af[i] = *reinterpret_cast<const bf16x8*>(&As[(wm * 64 + i * 16 + c) * 40 + g * 8]);
#pragma unroll
    for (int j = 0; j < 4; ++j)
      bfr[j] = *reinterpret_cast<const bf16x8*>(&Bs[(wn * 64 + j * 16 + c) * 40 + g * 8]);
#pragma unroll
    for (int i = 0; i < 4; ++i)
#pragma unroll
      for (int j = 0; j < 4; ++j)
        acc[i][j] = MFMA_BF16(af[i], bfr[j], acc[i][j]);
    __syncthreads();
  }

  const int which = o0 >> 9;  // 0=Q 1=K 2=V, uniform per block
#pragma unroll
  for (int i = 0; i < 4; ++i) {
    const int ob = o0 + wm * 64 + i * 16 + 4 * g;  // o of reg r=0
    float bias4[4];
#pragma unroll
    for (int r = 0; r < 4; ++r) bias4[r] = bias[ob + r];
    const int h = (ob >> 6) & 7;
    const int d0 = ob & 63;
#pragma unroll
    for (int j = 0; j < 4; ++j) {
      const int n = n0 + wn * 64 + j * 16 + c;
      if (which == 2) {
        bf16_t* vp = Vb + (size_t)(b * 8 + h) * 64 * NB + n;
#pragma unroll
        for (int r = 0; r < 4; ++r)
          vp[(size_t)(d0 + r) * NB] = (bf16_t)(acc[i][j][r] + bias4[r]);
      } else {
        bf16_t* qp = (which == 0 ? Qb : Kb) + ((size_t)(b * 8 + h) * NB + n) * 64 + d0;
        bf16x4 pk;
#pragma unroll
        for (int r = 0; r < 4; ++r) pk[r] = (bf16_t)(acc[i][j][r] + bias4[r]);
        *reinterpret_cast<bf16x4*>(qp) = pk;
      }
    }
  }
}

// ---------- k2: flash attention ----------
// Q,K: [bh][n][64], V: [bh][64][n].  Out: Obuf[b][n][c] bf16 (c = h*64+d).
__global__ __launch_bounds__(256) void k_attn(const bf16_t* __restrict__ Qb,
                                              const bf16_t* __restrict__ Kb,
                                              const bf16_t* __restrict__ Vb,
                                              bf16_t* __restrict__ Ob) {
  __shared__ __align__(16) bf16_t P_lds[4 * 1024];  // 2 KB per wave
  const int t = threadIdx.x, lane = t & 63, wv = t >> 6;
  const int g = lane >> 4, c = lane & 15;
  const int bh = blockIdx.y;
  const int q0 = blockIdx.x * 64;
  const size_t base = (size_t)bh * NB * 64;
  const bf16_t* Qp = Qb + base;
  const bf16_t* Kp = Kb + base;
  const bf16_t* Vp = Vb + base;

  const int qrow = q0 + wv * 16 + c;
  bf16x8 qf[2];
#pragma unroll
  for (int ks = 0; ks < 2; ++ks)
    qf[ks] = *reinterpret_cast<const bf16x8*>(Qp + (size_t)qrow * 64 + ks * 32 + g * 8);

  floatx4 O[4] = {};
  float m[4], l[4];
#pragma unroll
  for (int r = 0; r < 4; ++r) { m[r] = -1e30f; l[r] = 0.f; }

  const float SC = 0.125f * 1.44269504088896340736f;  // hd^-0.5 * log2(e)
  char* Pbase = reinterpret_cast<char*>(&P_lds[wv * 1024]);

  for (int kv0 = 0; kv0 < NB; kv0 += 64) {
    floatx4 S[4];
#pragma unroll
    for (int kt = 0; kt < 4; ++kt) {
      floatx4 s = {};
#pragma unroll
      for (int ks = 0; ks < 2; ++ks) {
        bf16x8 kf = *reinterpret_cast<const bf16x8*>(
            Kp + (size_t)(kv0 + kt * 16 + c) * 64 + ks * 32 + g * 8);
        s = MFMA_BF16(qf[ks], kf, s);
      }
      S[kt] = s * SC;
    }
    float mn[4], al[4], ps[4];
#pragma unroll
    for (int r = 0; r < 4; ++r) {
      float v = fmaxf(fmaxf(S[0][r], S[1][r]), fmaxf(S[2][r], S[3][r]));
#pragma unroll
      for (int msk = 1; msk <= 8; msk <<= 1) v = fmaxf(v, __shfl_xor(v, msk));
      mn[r] = fmaxf(m[r], v);
      al[r] = exp2f(m[r] - mn[r]);
      ps[r] = 0.f;
    }
#pragma unroll
    for (int kt = 0; kt < 4; ++kt)
#pragma unroll
      for (int r = 0; r < 4; ++r) {
        const float p = exp2f(S[kt][r] - mn[r]);
        S[kt][r] = p;
        ps[r] += p;
      }
#pragma unroll
    for (int r = 0; r < 4; ++r) {
#pragma unroll
      for (int msk = 1; msk <= 8; msk <<= 1) ps[r] += __shfl_xor(ps[r], msk);
      l[r] = l[r] * al[r] + ps[r];
      m[r] = mn[r];
    }
#pragma unroll
    for (int dt = 0; dt < 4; ++dt)
#pragma unroll
      for (int r = 0; r < 4; ++r) O[dt][r] *= al[r];

    // P -> LDS (bf16), XOR-swizzled to kill stride-128B bank conflicts
#pragma unroll
    for (int kt = 0; kt < 4; ++kt)
#pragma unroll
      for (int r = 0; r < 4; ++r) {
        const int row = 4 * g + r, col = kt * 16 + c;
        const int byo = (row * 128 + col * 2) ^ ((row & 7) << 4);
        *reinterpret_cast<bf16_t*>(Pbase + byo) = (bf16_t)S[kt][r];
      }
    // PV
#pragma unroll
    for (int dt = 0; dt < 4; ++dt)
#pragma unroll
      for (int ks = 0; ks < 2; ++ks) {
        const int byo = (c * 128 + ks * 64 + g * 16) ^ ((c & 7) << 4);
        bf16x8 pf = *reinterpret_cast<const bf16x8*>(Pbase + byo);
        bf16x8 vf = *reinterpret_cast<const bf16x8*>(
            Vp + (size_t)(dt * 16 + c) * NB + kv0 + ks * 32 + g * 8);
        O[dt] = MFMA_BF16(pf, vf, O[dt]);
      }
  }
  // epilogue: O/l -> Obuf[b][n][h*64+d]
  const int b = bh >> 3, h = bh & 7;
#pragma unroll
  for (int dt = 0; dt < 4; ++dt)
#pragma unroll
    for (int r = 0; r < 4; ++r) {
      const int n = q0 + wv * 16 + 4 * g + r;
      const float val = O[dt][r] / l[r];
      Ob[((size_t)(b * NB + n)) * CB + h * 64 + dt * 16 + c] = (bf16_t)val;
    }
}

// ---------- k3: out GEMM + bias + gamma*out + x ----------
__global__ __launch_bounds__(256) void k_out(const float* __restrict__ W,
                                             const float* __restrict__ bias,
                                             const bf16_t* __restrict__ Ob,
                                             const float* __restrict__ x,
                                             const float* __restrict__ gamma,
                                             float* __restrict__ y) {
  __shared__ __align__(16) bf16_t As[128 * 40];
  __shared__ __align__(16) bf16_t Bs[128 * 40];
  const int t = threadIdx.x;
  const int lane = t & 63, wv = t >> 6;
  const int g = lane >> 4, c = lane & 15;
  const int wm = wv >> 1, wn = wv & 1;
  const int o0 = blockIdx.x * 128, n0 = blockIdx.y * 128;
  const int b = blockIdx.z;

  floatx4 acc[4][4] = {};

  const float* Ap = W + (size_t)o0 * CB;
  const bf16_t* Bp = Ob + ((size_t)b * NB + n0) * CB;

  for (int kt = 0; kt < CB; kt += 32) {
    {
      const int row = t >> 3, c4 = (t & 7) * 4;
#pragma unroll
      for (int p = 0; p < 4; ++p) {
        const int r = row + p * 32;
        const float4 v = *reinterpret_cast<const float4*>(Ap + (size_t)r * CB + kt + c4);
        bf16x4 w4;
        w4[0] = (bf16_t)v.x; w4[1] = (bf16_t)v.y; w4[2] = (bf16_t)v.z; w4[3] = (bf16_t)v.w;
        *reinterpret_cast<bf16x4*>(&As[r * 40 + c4]) = w4;
      }
    }
    {
      const int row = t >> 2, ch = t & 3;
#pragma unroll
      for (int p = 0; p < 2; ++p) {
        const int r = row + p * 64;
        bf16x8 v = *reinterpret_cast<const bf16x8*>(Bp + (size_t)r * CB + kt + ch * 8);
        *reinterpret_cast<bf16x8*>(&Bs[r * 40 + ch * 8]) = v;
      }
    }
    __syncthreads();
    bf16x8 af[4], bfr[4];
#pragma unroll
    for (int i = 0; i < 4; ++i)
      af[i] = *reinterpret_cast<const bf16x8*>(&As[(wm * 64 + i * 16 + c) * 40 + g * 8]);
#pragma unroll
    for (int j = 0; j < 4; ++j)
      bfr[j] = *reinterpret_cast<const bf16x8*>(&Bs[(wn * 64 + j * 16 + c) * 40 + g * 8]);
#pragma unroll
    for (int i = 0; i < 4; ++i)
#pragma unroll
      for (int j = 0; j < 4; ++j)
        acc[i][j] = MFMA_BF16(af[i], bfr[j], acc[i][j]);
    __syncthreads();
  }

  const float gm = gamma[0];
#pragma unroll
  for (int i = 0; i < 4; ++i) {
    const int ob = o0 + wm * 64 + i * 16 + 4 * g;
    float bias4[4];
#pragma unroll
    for (int r = 0; r < 4; ++r) bias4[r] = bias[ob + r];
#pragma unroll
    for (int j = 0; j < 4; ++j) {
      const int n = n0 + wn * 64 + j * 16 + c;
      const float* xp = x + ((size_t)(b * CB + ob) * NB) + n;
      float* yp = y + ((size_t)(b * CB + ob) * NB) + n;
#pragma unroll
      for (int r = 0; r < 4; ++r)
        yp[(size_t)r * NB] = gm * (acc[i][j][r] + bias4[r]) + xp[(size_t)r * NB];
    }
  }
}

extern "C" void kernel_launch(void* const* d_in, const int* in_sizes, int n_in,
                              void* d_out, int out_size, void* d_ws, size_t ws_size,
                              hipStream_t stream) {
  const float* x      = (const float*)d_in[0];
  const float* w_qkv  = (const float*)d_in[1];
  const float* b_qkv  = (const float*)d_in[2];
  const float* w_out  = (const float*)d_in[3];
  const float* b_out  = (const float*)d_in[4];
  const float* gamma  = (const float*)d_in[5];
  float* y = (float*)d_out;

  const size_t CH = 4194304;  // 2*8*4096*64 elements per chunk
  bf16_t* Wp = (bf16_t*)d_ws;
  bf16_t* Qb = Wp;
  bf16_t* Kb = Wp + CH;
  bf16_t* Vb = Wp + 2 * CH;
  bf16_t* Ob = Wp + 3 * CH;
  bf16_t* xT = Wp + 4 * CH;

  k_transpose<<<dim3(64, 8, 2), 256, 0, stream>>>(x, xT);
  k_qkv<<<dim3(12, 32, 2), 256, 0, stream>>>(w_qkv, b_qkv, xT, Qb, Kb, Vb);
  k_attn<<<dim3(64, 16), 256, 0, stream>>>(Qb, Kb, Vb, Ob);
  k_out<<<dim3(4, 32, 2), 256, 0, stream>>>(w_out, b_out, Ob, x, gamma, y);
}

// Round 2
// 196.800 us; speedup vs baseline: 2.5699x; 2.5699x over previous
//
#include <hip/hip_runtime.h>
#include <hip/hip_bf16.h>

typedef __bf16 bf16_t;
typedef __bf16 bf16x8 __attribute__((ext_vector_type(8)));
typedef __bf16 bf16x4 __attribute__((ext_vector_type(4)));
typedef float floatx4 __attribute__((ext_vector_type(4)));
typedef float f32x16 __attribute__((ext_vector_type(16)));

#define MFMA_BF16(a, b, c) __builtin_amdgcn_mfma_f32_16x16x32_bf16((a), (b), (c), 0, 0, 0)
#define MFMA32(a, b, c) __builtin_amdgcn_mfma_f32_32x32x16_bf16((a), (b), (c), 0, 0, 0)

static constexpr int CB = 512;    // channels
static constexpr int NB = 4096;   // tokens (64*64)

__device__ __forceinline__ unsigned cvtpk_bf16(float lo, float hi_) {
  unsigned r;
  asm("v_cvt_pk_bf16_f32 %0, %1, %2" : "=v"(r) : "v"(lo), "v"(hi_));
  return r;
}
__device__ __forceinline__ void plswap(unsigned& x, unsigned& y) {
  asm volatile("v_permlane32_swap_b32 %0, %1" : "+v"(x), "+v"(y));
}

#define GLOAD_LDS16(gsrc, ldst)                                              \
  __builtin_amdgcn_global_load_lds(                                          \
      (const __attribute__((address_space(1))) void*)(gsrc),                 \
      (__attribute__((address_space(3))) void*)(ldst), 16, 0, 0)

// ---------- k0: x (b,c,n) f32 -> xT (b,n,c) bf16 ----------
__global__ __launch_bounds__(256) void k_transpose(const float* __restrict__ x,
                                                   bf16_t* __restrict__ xT) {
  __shared__ __align__(16) bf16_t T[64 * 72];
  const int t = threadIdx.x;
  const int b = blockIdx.z, c0 = blockIdx.y * 64, n0 = blockIdx.x * 64;
  {
    const int cl = t >> 4, nl = (t & 15) * 4;
#pragma unroll
    for (int p = 0; p < 4; ++p) {
      const int c = cl + p * 16;
      const float4 v = *reinterpret_cast<const float4*>(
          x + ((size_t)(b * CB + c0 + c) * NB) + n0 + nl);
      T[(nl + 0) * 72 + c] = (bf16_t)v.x;
      T[(nl + 1) * 72 + c] = (bf16_t)v.y;
      T[(nl + 2) * 72 + c] = (bf16_t)v.z;
      T[(nl + 3) * 72 + c] = (bf16_t)v.w;
    }
  }
  __syncthreads();
  {
    const int nr = t >> 2, ch = t & 3;
    bf16_t* op = xT + ((size_t)(b * NB + n0 + nr) * CB) + c0;
#pragma unroll
    for (int p = 0; p < 2; ++p) {
      bf16x8 v = *reinterpret_cast<const bf16x8*>(&T[nr * 72 + ch * 8 + p * 32]);
      *reinterpret_cast<bf16x8*>(op + ch * 8 + p * 32) = v;
    }
  }
}

// ---------- k1: QKV GEMM ----------
__global__ __launch_bounds__(256) void k_qkv(const float* __restrict__ W,
                                             const float* __restrict__ bias,
                                             const bf16_t* __restrict__ xT,
                                             bf16_t* __restrict__ Qb,
                                             bf16_t* __restrict__ Kb,
                                             bf16_t* __restrict__ Vb) {
  __shared__ __align__(16) bf16_t As[128 * 40];
  __shared__ __align__(16) bf16_t Bs[128 * 40];
  const int t = threadIdx.x;
  const int lane = t & 63, wv = t >> 6;
  const int g = lane >> 4, c = lane & 15;
  const int wm = wv >> 1, wn = wv & 1;
  const int o0 = blockIdx.x * 128, n0 = blockIdx.y * 128;
  const int b = blockIdx.z;

  floatx4 acc[4][4] = {};

  const float* Ap = W + (size_t)o0 * CB;
  const bf16_t* Bp = xT + ((size_t)b * NB + n0) * CB;

  for (int kt = 0; kt < CB; kt += 32) {
    {
      const int row = t >> 3, c4 = (t & 7) * 4;
#pragma unroll
      for (int p = 0; p < 4; ++p) {
        const int r = row + p * 32;
        const float4 v = *reinterpret_cast<const float4*>(Ap + (size_t)r * CB + kt + c4);
        bf16x4 w4;
        w4[0] = (bf16_t)v.x; w4[1] = (bf16_t)v.y; w4[2] = (bf16_t)v.z; w4[3] = (bf16_t)v.w;
        *reinterpret_cast<bf16x4*>(&As[r * 40 + c4]) = w4;
      }
    }
    {
      const int row = t >> 2, ch = t & 3;
#pragma unroll
      for (int p = 0; p < 2; ++p) {
        const int r = row + p * 64;
        bf16x8 v = *reinterpret_cast<const bf16x8*>(Bp + (size_t)r * CB + kt + ch * 8);
        *reinterpret_cast<bf16x8*>(&Bs[r * 40 + ch * 8]) = v;
      }
    }
    __syncthreads();
    bf16x8 af[4], bfr[4];
#pragma unroll
    for (int i = 0; i < 4; ++i)
      af[i] = *reinterpret_cast<const bf16x8*>(&As[(wm * 64 + i * 16 + c) * 40 + g * 8]);
#pragma unroll
    for (int j = 0; j < 4; ++j)
      bfr[j] = *reinterpret_cast<const bf16x8*>(&Bs[(wn * 64 + j * 16 + c) * 40 + g * 8]);
#pragma unroll
    for (int i = 0; i < 4; ++i)
#pragma unroll
      for (int j = 0; j < 4; ++j)
        acc[i][j] = MFMA_BF16(af[i], bfr[j], acc[i][j]);
    __syncthreads();
  }

  const int which = o0 >> 9;  // 0=Q 1=K 2=V
#pragma unroll
  for (int i = 0; i < 4; ++i) {
    const int ob = o0 + wm * 64 + i * 16 + 4 * g;
    float bias4[4];
#pragma unroll
    for (int r = 0; r < 4; ++r) bias4[r] = bias[ob + r];
    const int h = (ob >> 6) & 7;
    const int d0 = ob & 63;
#pragma unroll
    for (int j = 0; j < 4; ++j) {
      const int n = n0 + wn * 64 + j * 16 + c;
      if (which == 2) {
        bf16_t* vp = Vb + (size_t)(b * 8 + h) * 64 * NB + n;
#pragma unroll
        for (int r = 0; r < 4; ++r)
          vp[(size_t)(d0 + r) * NB] = (bf16_t)(acc[i][j][r] + bias4[r]);
      } else {
        bf16_t* qp = (which == 0 ? Qb : Kb) + ((size_t)(b * 8 + h) * NB + n) * 64 + d0;
        bf16x4 pk;
#pragma unroll
        for (int r = 0; r < 4; ++r) pk[r] = (bf16_t)(acc[i][j][r] + bias4[r]);
        *reinterpret_cast<bf16x4*>(qp) = pk;
      }
    }
  }
}

// ---------- k2: flash attention, 8 warps x 32 q-rows, 32x32x16 swapped-QK ----------
// Q,K: [bh][n][64], V: [bh][64][n].  Out: Ob[b][n][c] bf16.
__global__ __launch_bounds__(512) void k_attn(const bf16_t* __restrict__ Qb,
                                              const bf16_t* __restrict__ Kb,
                                              const bf16_t* __restrict__ Vb,
                                              bf16_t* __restrict__ Ob) {
  __shared__ __align__(16) bf16_t Kl[2][64 * 64];
  __shared__ __align__(16) bf16_t Vl[2][64 * 64];   // transposed: [d][kv]
  __shared__ __align__(16) float red[8][32];
  const int t = threadIdx.x, lane = t & 63, w = t >> 6;
  const int q31 = lane & 31, hi = lane >> 5;

  // XCD-bijective swizzle: 256 blocks, XCD x handles heads {2x,2x+1} (all 16 q-tiles)
  const int bid = blockIdx.x;
  const int xcd = bid & 7, j = bid >> 3;
  const int bh = xcd * 2 + (j >> 4), qt = j & 15;
  const int q0 = qt * 256 + w * 32;

  const size_t base = (size_t)bh * NB * 64;
  const bf16_t* Qp = Qb + base;
  const bf16_t* Kp = Kb + base;
  const bf16_t* Vp = Vb + base;

  // Q fragments (B-operand of S^T mfma): qf[ks] holds Q[q=lane&31][d=ks*16+hi*8 ..+8]
  bf16x8 qf[4];
#pragma unroll
  for (int ks = 0; ks < 4; ++ks)
    qf[ks] = *reinterpret_cast<const bf16x8*>(Qp + (size_t)(q0 + q31) * 64 + ks * 16 + hi * 8);

  // staging: thread t stages 16B chunk t of K-tile and of Vt-tile.
  // LDS dest linear (chunk t); global src column pre-swizzled: col16 ^= row&7.
  const int srow = t >> 3;
  const int scol8 = (((t & 7) ^ (srow & 7))) * 8;
  const bf16_t* ksrc = Kp + (size_t)srow * 64 + scol8;   // + kv0*64 per step
  const bf16_t* vsrc = Vp + (size_t)srow * NB + scol8;   // + kv0 per step

  // read-side swizzled chunk index per ks (row&7 == q31&7 for all row = {0,32,..}+q31)
  int c16r[4];
#pragma unroll
  for (int ks = 0; ks < 4; ++ks) c16r[ks] = ((ks * 2 + hi) ^ (q31 & 7)) * 8;

  f32x16 O0 = {}, O1 = {};
  float m = -1e30f, l = 0.f;
  const float SC = 0.125f * 1.44269504088896340736f;  // hd^-0.5 * log2(e)

  // prologue: stage tile 0
  GLOAD_LDS16(ksrc, &Kl[0][w * 512]);
  GLOAD_LDS16(vsrc, &Vl[0][w * 512]);
  __syncthreads();

  for (int s = 0; s < 64; ++s) {
    const bf16_t* Kbuf = Kl[s & 1];
    const bf16_t* Vbuf = Vl[s & 1];
    if (s < 63) {
      GLOAD_LDS16(ksrc + (size_t)(s + 1) * 64 * 64, &Kl[(s + 1) & 1][w * 512]);
      GLOAD_LDS16(vsrc + (s + 1) * 64, &Vl[(s + 1) & 1][w * 512]);
    }
    // S^T = K · Q^T : st0 = kv 0..31, st1 = kv 32..63 (rows), q = lane&31 (col)
    f32x16 st0 = {}, st1 = {};
#pragma unroll
    for (int ks = 0; ks < 4; ++ks) {
      bf16x8 kf0 = *reinterpret_cast<const bf16x8*>(&Kbuf[q31 * 64 + c16r[ks]]);
      bf16x8 kf1 = *reinterpret_cast<const bf16x8*>(&Kbuf[(32 + q31) * 64 + c16r[ks]]);
      st0 = MFMA32(kf0, qf[ks], st0);
      st1 = MFMA32(kf1, qf[ks], st1);
    }
    // online softmax, per-lane (q = lane&31): 32 in-lane scores + pair lane
    float rmax = st0[0];
#pragma unroll
    for (int r = 1; r < 16; ++r) rmax = fmaxf(rmax, st0[r]);
#pragma unroll
    for (int r = 0; r < 16; ++r) rmax = fmaxf(rmax, st1[r]);
    rmax = fmaxf(rmax, __shfl_xor(rmax, 32));
    const float mn = fmaxf(m, rmax * SC);
    const float al = exp2f(m - mn);
    float ps = 0.f;
#pragma unroll
    for (int r = 0; r < 16; ++r) {
      st0[r] = exp2f(fmaf(st0[r], SC, -mn));
      ps += st0[r];
    }
#pragma unroll
    for (int r = 0; r < 16; ++r) {
      st1[r] = exp2f(fmaf(st1[r], SC, -mn));
      ps += st1[r];
    }
    ps += __shfl_xor(ps, 32);
    l = l * al + ps;
    m = mn;

    // redistribute al by O-row via per-warp LDS (wave-synchronous)
    red[w][q31] = al;
    const float4 A0 = *reinterpret_cast<const float4*>(&red[w][4 * hi]);
    const float4 A1 = *reinterpret_cast<const float4*>(&red[w][8 + 4 * hi]);
    const float4 A2 = *reinterpret_cast<const float4*>(&red[w][16 + 4 * hi]);
    const float4 A3 = *reinterpret_cast<const float4*>(&red[w][24 + 4 * hi]);
    const float af4[16] = {A0.x, A0.y, A0.z, A0.w, A1.x, A1.y, A1.z, A1.w,
                           A2.x, A2.y, A2.z, A2.w, A3.x, A3.y, A3.z, A3.w};
#pragma unroll
    for (int r = 0; r < 16; ++r) { O0[r] *= af4[r]; O1[r] *= af4[r]; }

    // P -> bf16 A-frags (cvt_pk + permlane32_swap), then PV
#pragma unroll
    for (int ks = 0; ks < 4; ++ks) {
      const f32x16& P = (ks < 2) ? st0 : st1;
      const int rb = (ks & 1) * 8;
      unsigned x0 = cvtpk_bf16(P[rb + 0], P[rb + 1]);
      unsigned y0 = cvtpk_bf16(P[rb + 4], P[rb + 5]);
      unsigned x1 = cvtpk_bf16(P[rb + 2], P[rb + 3]);
      unsigned y1 = cvtpk_bf16(P[rb + 6], P[rb + 7]);
      plswap(x0, y0);
      plswap(x1, y1);
      union { unsigned u[4]; bf16x8 v; } pa;
      pa.u[0] = x0; pa.u[1] = x1; pa.u[2] = y0; pa.u[3] = y1;
      bf16x8 vf0 = *reinterpret_cast<const bf16x8*>(&Vbuf[q31 * 64 + c16r[ks]]);
      bf16x8 vf1 = *reinterpret_cast<const bf16x8*>(&Vbuf[(32 + q31) * 64 + c16r[ks]]);
      O0 = MFMA32(pa.v, vf0, O0);
      O1 = MFMA32(pa.v, vf1, O1);
    }
    __syncthreads();
  }

  // epilogue: scale by 1/l, store Ob[b][n][h*64 + d]
  const float linv = 1.0f / l;
  red[w][q31] = linv;
  const float4 L0 = *reinterpret_cast<const float4*>(&red[w][4 * hi]);
  const float4 L1 = *reinterpret_cast<const float4*>(&red[w][8 + 4 * hi]);
  const float4 L2 = *reinterpret_cast<const float4*>(&red[w][16 + 4 * hi]);
  const float4 L3 = *reinterpret_cast<const float4*>(&red[w][24 + 4 * hi]);
  const float lf[16] = {L0.x, L0.y, L0.z, L0.w, L1.x, L1.y, L1.z, L1.w,
                        L2.x, L2.y, L2.z, L2.w, L3.x, L3.y, L3.z, L3.w};
  const int b = bh >> 3, h = bh & 7;
#pragma unroll
  for (int r = 0; r < 16; ++r) {
    const int n = q0 + (r & 3) + 8 * (r >> 2) + 4 * hi;
    bf16_t* op = Ob + ((size_t)(b * NB + n)) * CB + h * 64 + q31;
    op[0]  = (bf16_t)(O0[r] * lf[r]);
    op[32] = (bf16_t)(O1[r] * lf[r]);
  }
}

// ---------- k3: out GEMM + bias + gamma*out + x ----------
__global__ __launch_bounds__(256) void k_out(const float* __restrict__ W,
                                             const float* __restrict__ bias,
                                             const bf16_t* __restrict__ Ob,
                                             const float* __restrict__ x,
                                             const float* __restrict__ gamma,
                                             float* __restrict__ y) {
  __shared__ __align__(16) bf16_t As[128 * 40];
  __shared__ __align__(16) bf16_t Bs[128 * 40];
  const int t = threadIdx.x;
  const int lane = t & 63, wv = t >> 6;
  const int g = lane >> 4, c = lane & 15;
  const int wm = wv >> 1, wn = wv & 1;
  const int o0 = blockIdx.x * 128, n0 = blockIdx.y * 128;
  const int b = blockIdx.z;

  floatx4 acc[4][4] = {};

  const float* Ap = W + (size_t)o0 * CB;
  const bf16_t* Bp = Ob + ((size_t)b * NB + n0) * CB;

  for (int kt = 0; kt < CB; kt += 32) {
    {
      const int row = t >> 3, c4 = (t & 7) * 4;
#pragma unroll
      for (int p = 0; p < 4; ++p) {
        const int r = row + p * 32;
        const float4 v = *reinterpret_cast<const float4*>(Ap + (size_t)r * CB + kt + c4);
        bf16x4 w4;
        w4[0] = (bf16_t)v.x; w4[1] = (bf16_t)v.y; w4[2] = (bf16_t)v.z; w4[3] = (bf16_t)v.w;
        *reinterpret_cast<bf16x4*>(&As[r * 40 + c4]) = w4;
      }
    }
    {
      const int row = t >> 2, ch = t & 3;
#pragma unroll
      for (int p = 0; p < 2; ++p) {
        const int r = row + p * 64;
        bf16x8 v = *reinterpret_cast<const bf16x8*>(Bp + (size_t)r * CB + kt + ch * 8);
        *reinterpret_cast<bf16x8*>(&Bs[r * 40 + ch * 8]) = v;
      }
    }
    __syncthreads();
    bf16x8 af[4], bfr[4];
#pragma unroll
    for (int i = 0; i < 4; ++i)
      af[i] = *reinterpret_cast<const bf16x8*>(&As[(wm * 64 + i * 16 + c) * 40 + g * 8]);
#pragma unroll
    for (int j = 0; j < 4; ++j)
      bfr[j] = *reinterpret_cast<const bf16x8*>(&Bs[(wn * 64 + j * 16 + c) * 40 + g * 8]);
#pragma unroll
    for (int i = 0; i < 4; ++i)
#pragma unroll
      for (int j = 0; j < 4; ++j)
        acc[i][j] = MFMA_BF16(af[i], bfr[j], acc[i][j]);
    __syncthreads();
  }

  const float gm = gamma[0];
#pragma unroll
  for (int i = 0; i < 4; ++i) {
    const int ob = o0 + wm * 64 + i * 16 + 4 * g;
    float bias4[4];
#pragma unroll
    for (int r = 0; r < 4; ++r) bias4[r] = bias[ob + r];
#pragma unroll
    for (int j = 0; j < 4; ++j) {
      const int n = n0 + wn * 64 + j * 16 + c;
      const float* xp = x + ((size_t)(b * CB + ob) * NB) + n;
      float* yp = y + ((size_t)(b * CB + ob) * NB) + n;
#pragma unroll
      for (int r = 0; r < 4; ++r)
        yp[(size_t)r * NB] = gm * (acc[i][j][r] + bias4[r]) + xp[(size_t)r * NB];
    }
  }
}

extern "C" void kernel_launch(void* const* d_in, const int* in_sizes, int n_in,
                              void* d_out, int out_size, void* d_ws, size_t ws_size,
                              hipStream_t stream) {
  const float* x      = (const float*)d_in[0];
  const float* w_qkv  = (const float*)d_in[1];
  const float* b_qkv  = (const float*)d_in[2];
  const float* w_out  = (const float*)d_in[3];
  const float* b_out  = (const float*)d_in[4];
  const float* gamma  = (const float*)d_in[5];
  float* y = (float*)d_out;

  const size_t CH = 4194304;  // 2*8*4096*64 elements per chunk
  bf16_t* Wp = (bf16_t*)d_ws;
  bf16_t* Qb = Wp;
  bf16_t* Kb = Wp + CH;
  bf16_t* Vb = Wp + 2 * CH;
  bf16_t* Ob = Wp + 3 * CH;
  bf16_t* xT = Wp + 4 * CH;

  k_transpose<<<dim3(64, 8, 2), 256, 0, stream>>>(x, xT);
  k_qkv<<<dim3(12, 32, 2), 256, 0, stream>>>(w_qkv, b_qkv, xT, Qb, Kb, Vb);
  k_attn<<<dim3(256), 512, 0, stream>>>(Qb, Kb, Vb, Ob);
  k_out<<<dim3(4, 32, 2), 256, 0, stream>>>(w_out, b_out, Ob, x, gamma, y);
}

// Round 3
// 182.369 us; speedup vs baseline: 2.7733x; 1.0791x over previous
//
#include <hip/hip_runtime.h>
#include <hip/hip_bf16.h>

typedef __bf16 bf16_t;
typedef __bf16 bf16x8 __attribute__((ext_vector_type(8)));
typedef __bf16 bf16x4 __attribute__((ext_vector_type(4)));
typedef float floatx4 __attribute__((ext_vector_type(4)));
typedef float f32x16 __attribute__((ext_vector_type(16)));

#define MFMA_BF16(a, b, c) __builtin_amdgcn_mfma_f32_16x16x32_bf16((a), (b), (c), 0, 0, 0)
#define MFMA32(a, b, c) __builtin_amdgcn_mfma_f32_32x32x16_bf16((a), (b), (c), 0, 0, 0)

static constexpr int CB = 512;    // channels
static constexpr int NB = 4096;   // tokens (64*64)

__device__ __forceinline__ unsigned cvtpk_bf16(float lo, float hi_) {
  unsigned r;
  asm("v_cvt_pk_bf16_f32 %0, %1, %2" : "=v"(r) : "v"(lo), "v"(hi_));
  return r;
}
__device__ __forceinline__ void plswap(unsigned& x, unsigned& y) {
  asm volatile("v_permlane32_swap_b32 %0, %1" : "+v"(x), "+v"(y));
}

#define GLOAD_LDS16(gsrc, ldst)                                              \
  __builtin_amdgcn_global_load_lds(                                          \
      (const __attribute__((address_space(1))) void*)(gsrc),                 \
      (__attribute__((address_space(3))) void*)(ldst), 16, 0, 0)

// ---------- k0: x (b,c,n) f32 -> xT (b,n,c) bf16 ----------
__global__ __launch_bounds__(256) void k_transpose(const float* __restrict__ x,
                                                   bf16_t* __restrict__ xT) {
  __shared__ __align__(16) bf16_t T[64 * 72];
  const int t = threadIdx.x;
  const int b = blockIdx.z, c0 = blockIdx.y * 64, n0 = blockIdx.x * 64;
  {
    const int cl = t >> 4, nl = (t & 15) * 4;
#pragma unroll
    for (int p = 0; p < 4; ++p) {
      const int c = cl + p * 16;
      const float4 v = *reinterpret_cast<const float4*>(
          x + ((size_t)(b * CB + c0 + c) * NB) + n0 + nl);
      T[(nl + 0) * 72 + c] = (bf16_t)v.x;
      T[(nl + 1) * 72 + c] = (bf16_t)v.y;
      T[(nl + 2) * 72 + c] = (bf16_t)v.z;
      T[(nl + 3) * 72 + c] = (bf16_t)v.w;
    }
  }
  __syncthreads();
  {
    const int nr = t >> 2, ch = t & 3;
    bf16_t* op = xT + ((size_t)(b * NB + n0 + nr) * CB) + c0;
#pragma unroll
    for (int p = 0; p < 2; ++p) {
      bf16x8 v = *reinterpret_cast<const bf16x8*>(&T[nr * 72 + ch * 8 + p * 32]);
      *reinterpret_cast<bf16x8*>(op + ch * 8 + p * 32) = v;
    }
  }
}

// ---------- k1: QKV GEMM ----------
__global__ __launch_bounds__(256) void k_qkv(const float* __restrict__ W,
                                             const float* __restrict__ bias,
                                             const bf16_t* __restrict__ xT,
                                             bf16_t* __restrict__ Qb,
                                             bf16_t* __restrict__ Kb,
                                             bf16_t* __restrict__ Vb) {
  __shared__ __align__(16) bf16_t As[128 * 40];
  __shared__ __align__(16) bf16_t Bs[128 * 40];
  const int t = threadIdx.x;
  const int lane = t & 63, wv = t >> 6;
  const int g = lane >> 4, c = lane & 15;
  const int wm = wv >> 1, wn = wv & 1;
  const int o0 = blockIdx.x * 128, n0 = blockIdx.y * 128;
  const int b = blockIdx.z;

  floatx4 acc[4][4] = {};

  const float* Ap = W + (size_t)o0 * CB;
  const bf16_t* Bp = xT + ((size_t)b * NB + n0) * CB;

  for (int kt = 0; kt < CB; kt += 32) {
    {
      const int row = t >> 3, c4 = (t & 7) * 4;
#pragma unroll
      for (int p = 0; p < 4; ++p) {
        const int r = row + p * 32;
        const float4 v = *reinterpret_cast<const float4*>(Ap + (size_t)r * CB + kt + c4);
        bf16x4 w4;
        w4[0] = (bf16_t)v.x; w4[1] = (bf16_t)v.y; w4[2] = (bf16_t)v.z; w4[3] = (bf16_t)v.w;
        *reinterpret_cast<bf16x4*>(&As[r * 40 + c4]) = w4;
      }
    }
    {
      const int row = t >> 2, ch = t & 3;
#pragma unroll
      for (int p = 0; p < 2; ++p) {
        const int r = row + p * 64;
        bf16x8 v = *reinterpret_cast<const bf16x8*>(Bp + (size_t)r * CB + kt + ch * 8);
        *reinterpret_cast<bf16x8*>(&Bs[r * 40 + ch * 8]) = v;
      }
    }
    __syncthreads();
    bf16x8 af[4], bfr[4];
#pragma unroll
    for (int i = 0; i < 4; ++i)
      af[i] = *reinterpret_cast<const bf16x8*>(&As[(wm * 64 + i * 16 + c) * 40 + g * 8]);
#pragma unroll
    for (int j = 0; j < 4; ++j)
      bfr[j] = *reinterpret_cast<const bf16x8*>(&Bs[(wn * 64 + j * 16 + c) * 40 + g * 8]);
#pragma unroll
    for (int i = 0; i < 4; ++i)
#pragma unroll
      for (int j = 0; j < 4; ++j)
        acc[i][j] = MFMA_BF16(af[i], bfr[j], acc[i][j]);
    __syncthreads();
  }

  const int which = o0 >> 9;  // 0=Q 1=K 2=V
#pragma unroll
  for (int i = 0; i < 4; ++i) {
    const int ob = o0 + wm * 64 + i * 16 + 4 * g;
    float bias4[4];
#pragma unroll
    for (int r = 0; r < 4; ++r) bias4[r] = bias[ob + r];
    const int h = (ob >> 6) & 7;
    const int d0 = ob & 63;
#pragma unroll
    for (int j = 0; j < 4; ++j) {
      const int n = n0 + wn * 64 + j * 16 + c;
      if (which == 2) {
        bf16_t* vp = Vb + (size_t)(b * 8 + h) * 64 * NB + n;
#pragma unroll
        for (int r = 0; r < 4; ++r)
          vp[(size_t)(d0 + r) * NB] = (bf16_t)(acc[i][j][r] + bias4[r]);
      } else {
        bf16_t* qp = (which == 0 ? Qb : Kb) + ((size_t)(b * 8 + h) * NB + n) * 64 + d0;
        bf16x4 pk;
#pragma unroll
        for (int r = 0; r < 4; ++r) pk[r] = (bf16_t)(acc[i][j][r] + bias4[r]);
        *reinterpret_cast<bf16x4*>(qp) = pk;
      }
    }
  }
}

// ---------- k2: flash attention, 4 warps x 32 q-rows, 32x32x16 swapped-QK ----------
// Q,K: [bh][n][64], V: [bh][64][n].  Out: Ob[b][n][c] bf16.
__global__ __launch_bounds__(256) void k_attn(const bf16_t* __restrict__ Qb,
                                              const bf16_t* __restrict__ Kb,
                                              const bf16_t* __restrict__ Vb,
                                              bf16_t* __restrict__ Ob) {
  __shared__ __align__(16) bf16_t Kl[2][64 * 64];
  __shared__ __align__(16) bf16_t Vl[2][64 * 64];   // transposed: [d][kv]
  __shared__ __align__(16) float red[4][32];
  const int t = threadIdx.x, lane = t & 63, w = t >> 6;
  const int q31 = lane & 31, hi = lane >> 5;

  // XCD-bijective swizzle: 512 blocks, XCD x handles heads {2x,2x+1} (32 q-tiles each)
  const int bid = blockIdx.x;
  const int xcd = bid & 7, j = bid >> 3;
  const int bh = xcd * 2 + (j >> 5), qt = j & 31;
  const int q0 = qt * 128 + w * 32;

  const size_t base = (size_t)bh * NB * 64;
  const bf16_t* Qp = Qb + base;
  const bf16_t* Kp = Kb + base;
  const bf16_t* Vp = Vb + base;

  const float SC = 0.125f * 1.44269504088896340736f;  // hd^-0.5 * log2(e)

  // Q fragments (B-operand of S^T mfma), pre-scaled by SC so scores are log2-domain
  bf16x8 qf[4];
#pragma unroll
  for (int ks = 0; ks < 4; ++ks) {
    bf16x8 q = *reinterpret_cast<const bf16x8*>(Qp + (size_t)(q0 + q31) * 64 + ks * 16 + hi * 8);
#pragma unroll
    for (int e = 0; e < 8; ++e) q[e] = (bf16_t)((float)q[e] * SC);
    qf[ks] = q;
  }

  // staging: 256 threads stage 512 chunks of 16B per tensor (2 each).
  // LDS dest linear; global src column pre-swizzled: chunk8 ^= row&7.
  const int srow0 = t >> 3, srow1 = srow0 + 32;
  const int sc0 = ((t & 7) ^ (srow0 & 7)) * 8;
  const int sc1 = ((t & 7) ^ (srow1 & 7)) * 8;
  const bf16_t* ksrc0 = Kp + (size_t)srow0 * 64 + sc0;
  const bf16_t* ksrc1 = Kp + (size_t)srow1 * 64 + sc1;
  const bf16_t* vsrc0 = Vp + (size_t)srow0 * NB + sc0;
  const bf16_t* vsrc1 = Vp + (size_t)srow1 * NB + sc1;

  // read-side swizzled chunk offsets
  int c16r[4];
#pragma unroll
  for (int ks = 0; ks < 4; ++ks) c16r[ks] = ((ks * 2 + hi) ^ (q31 & 7)) * 8;

  f32x16 O0 = {}, O1 = {};
  float m = -1e30f, l = 0.f;

  // prologue: stage tile 0
  GLOAD_LDS16(ksrc0, &Kl[0][w * 512]);
  GLOAD_LDS16(ksrc1, &Kl[0][2048 + w * 512]);
  GLOAD_LDS16(vsrc0, &Vl[0][w * 512]);
  GLOAD_LDS16(vsrc1, &Vl[0][2048 + w * 512]);
  __syncthreads();

  for (int s = 0; s < 64; ++s) {
    const bf16_t* Kbuf = Kl[s & 1];
    const bf16_t* Vbuf = Vl[s & 1];
    if (s < 63) {
      const size_t ko = (size_t)(s + 1) * 64 * 64;
      const int vo = (s + 1) * 64;
      bf16_t* kd = &Kl[(s + 1) & 1][0];
      bf16_t* vd = &Vl[(s + 1) & 1][0];
      GLOAD_LDS16(ksrc0 + ko, kd + w * 512);
      GLOAD_LDS16(ksrc1 + ko, kd + 2048 + w * 512);
      GLOAD_LDS16(vsrc0 + vo, vd + w * 512);
      GLOAD_LDS16(vsrc1 + vo, vd + 2048 + w * 512);
    }
    // S^T = K · Q^T (log2-domain scores)
    f32x16 st0 = {}, st1 = {};
    __builtin_amdgcn_s_setprio(1);
#pragma unroll
    for (int ks = 0; ks < 4; ++ks) {
      bf16x8 kf0 = *reinterpret_cast<const bf16x8*>(&Kbuf[q31 * 64 + c16r[ks]]);
      bf16x8 kf1 = *reinterpret_cast<const bf16x8*>(&Kbuf[(32 + q31) * 64 + c16r[ks]]);
      st0 = MFMA32(kf0, qf[ks], st0);
      st1 = MFMA32(kf1, qf[ks], st1);
    }
    __builtin_amdgcn_s_setprio(0);
    // row max (nested triples -> v_max3)
    float rmax = fmaxf(st0[0], st0[1]);
#pragma unroll
    for (int r = 2; r < 16; r += 2) rmax = fmaxf(fmaxf(st0[r], st0[r + 1]), rmax);
#pragma unroll
    for (int r = 0; r < 16; r += 2) rmax = fmaxf(fmaxf(st1[r], st1[r + 1]), rmax);
    rmax = fmaxf(rmax, __shfl_xor(rmax, 32));

    // defer-max: rescale only when the running max moved by > 8 (log2 units)
    if (!__all(rmax <= m + 8.f)) {
      const float mn = fmaxf(m, rmax);
      const float al = exp2f(m - mn);
      m = mn;
      l *= al;
      red[w][q31] = al;
      const float4 A0 = *reinterpret_cast<const float4*>(&red[w][4 * hi]);
      const float4 A1 = *reinterpret_cast<const float4*>(&red[w][8 + 4 * hi]);
      const float4 A2 = *reinterpret_cast<const float4*>(&red[w][16 + 4 * hi]);
      const float4 A3 = *reinterpret_cast<const float4*>(&red[w][24 + 4 * hi]);
      const float af4[16] = {A0.x, A0.y, A0.z, A0.w, A1.x, A1.y, A1.z, A1.w,
                             A2.x, A2.y, A2.z, A2.w, A3.x, A3.y, A3.z, A3.w};
#pragma unroll
      for (int r = 0; r < 16; ++r) { O0[r] *= af4[r]; O1[r] *= af4[r]; }
    }

    float ps = 0.f;
#pragma unroll
    for (int r = 0; r < 16; ++r) {
      st0[r] = exp2f(st0[r] - m);
      ps += st0[r];
    }
#pragma unroll
    for (int r = 0; r < 16; ++r) {
      st1[r] = exp2f(st1[r] - m);
      ps += st1[r];
    }
    ps += __shfl_xor(ps, 32);
    l += ps;

    // P -> bf16 A-frags (cvt_pk + permlane32_swap), then PV
    __builtin_amdgcn_s_setprio(1);
#pragma unroll
    for (int ks = 0; ks < 4; ++ks) {
      const f32x16& P = (ks < 2) ? st0 : st1;
      const int rb = (ks & 1) * 8;
      unsigned x0 = cvtpk_bf16(P[rb + 0], P[rb + 1]);
      unsigned y0 = cvtpk_bf16(P[rb + 4], P[rb + 5]);
      unsigned x1 = cvtpk_bf16(P[rb + 2], P[rb + 3]);
      unsigned y1 = cvtpk_bf16(P[rb + 6], P[rb + 7]);
      plswap(x0, y0);
      plswap(x1, y1);
      union { unsigned u[4]; bf16x8 v; } pa;
      pa.u[0] = x0; pa.u[1] = x1; pa.u[2] = y0; pa.u[3] = y1;
      bf16x8 vf0 = *reinterpret_cast<const bf16x8*>(&Vbuf[q31 * 64 + c16r[ks]]);
      bf16x8 vf1 = *reinterpret_cast<const bf16x8*>(&Vbuf[(32 + q31) * 64 + c16r[ks]]);
      O0 = MFMA32(pa.v, vf0, O0);
      O1 = MFMA32(pa.v, vf1, O1);
    }
    __builtin_amdgcn_s_setprio(0);
    __syncthreads();
  }

  // epilogue: scale by 1/l, store Ob[b][n][h*64 + d]
  const float linv = 1.0f / l;
  red[w][q31] = linv;
  const float4 L0 = *reinterpret_cast<const float4*>(&red[w][4 * hi]);
  const float4 L1 = *reinterpret_cast<const float4*>(&red[w][8 + 4 * hi]);
  const float4 L2 = *reinterpret_cast<const float4*>(&red[w][16 + 4 * hi]);
  const float4 L3 = *reinterpret_cast<const float4*>(&red[w][24 + 4 * hi]);
  const float lf[16] = {L0.x, L0.y, L0.z, L0.w, L1.x, L1.y, L1.z, L1.w,
                        L2.x, L2.y, L2.z, L2.w, L3.x, L3.y, L3.z, L3.w};
  const int b = bh >> 3, h = bh & 7;
#pragma unroll
  for (int r = 0; r < 16; ++r) {
    const int n = q0 + (r & 3) + 8 * (r >> 2) + 4 * hi;
    bf16_t* op = Ob + ((size_t)(b * NB + n)) * CB + h * 64 + q31;
    op[0]  = (bf16_t)(O0[r] * lf[r]);
    op[32] = (bf16_t)(O1[r] * lf[r]);
  }
}

// ---------- k3: out GEMM + bias + gamma*out + x ----------
__global__ __launch_bounds__(256) void k_out(const float* __restrict__ W,
                                             const float* __restrict__ bias,
                                             const bf16_t* __restrict__ Ob,
                                             const float* __restrict__ x,
                                             const float* __restrict__ gamma,
                                             float* __restrict__ y) {
  __shared__ __align__(16) bf16_t As[128 * 40];
  __shared__ __align__(16) bf16_t Bs[128 * 40];
  const int t = threadIdx.x;
  const int lane = t & 63, wv = t >> 6;
  const int g = lane >> 4, c = lane & 15;
  const int wm = wv >> 1, wn = wv & 1;
  const int o0 = blockIdx.x * 128, n0 = blockIdx.y * 128;
  const int b = blockIdx.z;

  floatx4 acc[4][4] = {};

  const float* Ap = W + (size_t)o0 * CB;
  const bf16_t* Bp = Ob + ((size_t)b * NB + n0) * CB;

  for (int kt = 0; kt < CB; kt += 32) {
    {
      const int row = t >> 3, c4 = (t & 7) * 4;
#pragma unroll
      for (int p = 0; p < 4; ++p) {
        const int r = row + p * 32;
        const float4 v = *reinterpret_cast<const float4*>(Ap + (size_t)r * CB + kt + c4);
        bf16x4 w4;
        w4[0] = (bf16_t)v.x; w4[1] = (bf16_t)v.y; w4[2] = (bf16_t)v.z; w4[3] = (bf16_t)v.w;
        *reinterpret_cast<bf16x4*>(&As[r * 40 + c4]) = w4;
      }
    }
    {
      const int row = t >> 2, ch = t & 3;
#pragma unroll
      for (int p = 0; p < 2; ++p) {
        const int r = row + p * 64;
        bf16x8 v = *reinterpret_cast<const bf16x8*>(Bp + (size_t)r * CB + kt + ch * 8);
        *reinterpret_cast<bf16x8*>(&Bs[r * 40 + ch * 8]) = v;
      }
    }
    __syncthreads();
    bf16x8 af[4], bfr[4];
#pragma unroll
    for (int i = 0; i < 4; ++i)
      af[i] = *reinterpret_cast<const bf16x8*>(&As[(wm * 64 + i * 16 + c) * 40 + g * 8]);
#pragma unroll
    for (int j = 0; j < 4; ++j)
      bfr[j] = *reinterpret_cast<const bf16x8*>(&Bs[(wn * 64 + j * 16 + c) * 40 + g * 8]);
#pragma unroll
    for (int i = 0; i < 4; ++i)
#pragma unroll
      for (int j = 0; j < 4; ++j)
        acc[i][j] = MFMA_BF16(af[i], bfr[j], acc[i][j]);
    __syncthreads();
  }

  const float gm = gamma[0];
#pragma unroll
  for (int i = 0; i < 4; ++i) {
    const int ob = o0 + wm * 64 + i * 16 + 4 * g;
    float bias4[4];
#pragma unroll
    for (int r = 0; r < 4; ++r) bias4[r] = bias[ob + r];
#pragma unroll
    for (int j = 0; j < 4; ++j) {
      const int n = n0 + wn * 64 + j * 16 + c;
      const float* xp = x + ((size_t)(b * CB + ob) * NB) + n;
      float* yp = y + ((size_t)(b * CB + ob) * NB) + n;
#pragma unroll
      for (int r = 0; r < 4; ++r)
        yp[(size_t)r * NB] = gm * (acc[i][j][r] + bias4[r]) + xp[(size_t)r * NB];
    }
  }
}

extern "C" void kernel_launch(void* const* d_in, const int* in_sizes, int n_in,
                              void* d_out, int out_size, void* d_ws, size_t ws_size,
                              hipStream_t stream) {
  const float* x      = (const float*)d_in[0];
  const float* w_qkv  = (const float*)d_in[1];
  const float* b_qkv  = (const float*)d_in[2];
  const float* w_out  = (const float*)d_in[3];
  const float* b_out  = (const float*)d_in[4];
  const float* gamma  = (const float*)d_in[5];
  float* y = (float*)d_out;

  const size_t CH = 4194304;  // 2*8*4096*64 elements per chunk
  bf16_t* Wp = (bf16_t*)d_ws;
  bf16_t* Qb = Wp;
  bf16_t* Kb = Wp + CH;
  bf16_t* Vb = Wp + 2 * CH;
  bf16_t* Ob = Wp + 3 * CH;
  bf16_t* xT = Wp + 4 * CH;

  k_transpose<<<dim3(64, 8, 2), 256, 0, stream>>>(x, xT);
  k_qkv<<<dim3(12, 32, 2), 256, 0, stream>>>(w_qkv, b_qkv, xT, Qb, Kb, Vb);
  k_attn<<<dim3(512), 256, 0, stream>>>(Qb, Kb, Vb, Ob);
  k_out<<<dim3(4, 32, 2), 256, 0, stream>>>(w_out, b_out, Ob, x, gamma, y);
}